// Round 3
// baseline (338.142 us; speedup 1.0000x reference)
//
#include <hip/hip_runtime.h>

// z[b,d] = x[b,d] * (1 + sum_{i=1..K} w[i-1,d] * x[b,(d+i) mod D])
// B=8192, D=4096, K=16, fp32. HBM-bound: ~204 MB real HBM traffic/dispatch
// (L3 serves ~half of x across iterations) -> ~35-43 us floor.
//
// R2 (86 us): LDS burst + __syncthreads -> barrier drains vmcnt(0); latency-bound.
// R3 (96 us): register ping-pong pipeline. FAILED: VGPR=68 proves the compiler
//   rematerialized wv[16] (64 regs) inside the row loop, collapsing the
//   pipeline to depth ~0. Lesson: per-wave ILP pipelines are fragile under
//   hipcc regalloc.
// R4 (this): pure TLP. One thread per output float4, NO loop, no LDS, no
//   persistent registers. 131072 waves; each wave has up to 21 independent
//   loads in flight; waitcnt stalls only the issuing wave. This is the
//   copy-kernel regime (6.3 TB/s achievable). w re-reads per row are L1/L2
//   hits (w=256 KB, L2-resident; ~537 MB L2 traffic = ~12 TB/s << 34.5 ceiling).

#define D 4096
#define DG 1024          // D/4 float4 column-groups per row
#define K 16
#define TPB 256

typedef float f32x4 __attribute__((ext_vector_type(4)));

__global__ __launch_bounds__(TPB) void quad_enhancer_kernel(
    const float* __restrict__ x, const float* __restrict__ w,
    float* __restrict__ out) {
  const int gid = blockIdx.x * TPB + threadIdx.x;
  const int cg = gid & (DG - 1);       // column-group within row
  const int b = gid >> 10;             // row (log2(DG) = 10)

  const float4* __restrict__ xr = (const float4*)x + (size_t)b * DG;
  const float4* __restrict__ w4 = (const float4*)w;

  // 5 overlapping float4 loads = the 20 consecutive floats this thread needs.
  // Wave-wide each is one coalesced ~1KB transaction; 4/5 hit L1.
  // Wrap only matters for cg >= DG-4 (one wave per row has split addresses).
  float4 v0 = xr[cg];
  float4 v1 = xr[(cg + 1) & (DG - 1)];
  float4 v2 = xr[(cg + 2) & (DG - 1)];
  float4 v3 = xr[(cg + 3) & (DG - 1)];
  float4 v4 = xr[(cg + 4) & (DG - 1)];

  float xs[20];
  xs[0] = v0.x; xs[1] = v0.y; xs[2] = v0.z; xs[3] = v0.w;
  xs[4] = v1.x; xs[5] = v1.y; xs[6] = v1.z; xs[7] = v1.w;
  xs[8] = v2.x; xs[9] = v2.y; xs[10] = v2.z; xs[11] = v2.w;
  xs[12] = v3.x; xs[13] = v3.y; xs[14] = v3.z; xs[15] = v3.w;
  xs[16] = v4.x; xs[17] = v4.y; xs[18] = v4.z; xs[19] = v4.w;

  // 16 w loads (L2-hot, wave-coalesced) interleaved with FMAs by the
  // scheduler — all independent, so they pipeline freely.
  float ax = 1.0f, ay = 1.0f, az = 1.0f, aw = 1.0f;
#pragma unroll
  for (int i = 0; i < K; ++i) {
    float4 wv = w4[i * DG + cg];
    ax = fmaf(wv.x, xs[i + 1], ax);
    ay = fmaf(wv.y, xs[i + 2], ay);
    az = fmaf(wv.z, xs[i + 3], az);
    aw = fmaf(wv.w, xs[i + 4], aw);
  }

  f32x4 o;
  o.x = xs[0] * ax;
  o.y = xs[1] * ay;
  o.z = xs[2] * az;
  o.w = xs[3] * aw;
  // nt store: keep x (not out) resident in L3 across dispatches.
  __builtin_nontemporal_store(o, (f32x4*)out + (size_t)b * DG + cg);
}

extern "C" void kernel_launch(void* const* d_in, const int* in_sizes, int n_in,
                              void* d_out, int out_size, void* d_ws, size_t ws_size,
                              hipStream_t stream) {
  const float* x = (const float*)d_in[0];
  const float* w = (const float*)d_in[1];
  float* out = (float*)d_out;
  const int B = in_sizes[0] / D;  // 8192

  const int nblocks = (B * DG) / TPB;  // 32768 blocks, 1 thread per float4
  quad_enhancer_kernel<<<dim3(nblocks), dim3(TPB), 0, stream>>>(x, w, out);
}

// Round 4
// 277.703 us; speedup vs baseline: 1.2176x; 1.2176x over previous
//
#include <hip/hip_runtime.h>

// z[b,d] = x[b,d] * (1 + sum_{i=1..K} w[i-1,d] * x[b,(d+i) mod D])
// B=8192, D=4096, K=16, fp32. HBM floor: ~204 MB real traffic -> ~32-43 us.
//
// R2 (86 us): LDS burst + __syncthreads: barrier drains vmcnt -> latency-bound.
// R3 (96 us): reg ping-pong, wv[16] in regs. FAILED: VGPR=68 -> compiler
//   REMATERIALIZED wv inside the row loop (reload from cache each row),
//   collapsing both w-reuse and the prefetch pipeline.
// R4 (187 us): 1 thread/output, no w reuse. FAILED: occupancy 80% but BW
//   1.09 TB/s -> w re-reads (16 loads/output, ~2.1 GB L1/L2 traffic) thrash
//   L1 (per-wave footprint ~20KB x 26 waves >> 32KB) and clog the memory
//   pipe with L2-latency requests. Lesson: w reuse across rows is mandatory.
// R5 (this): R3 structure + asm-pin on wv. Empty asm volatile "+v" makes
//   each wv component opaque -> remat impossible -> 64 VGPRs stay live and
//   the ping-pong prefetch survives regalloc. Row loop fully unrolled so
//   all buffer indexing is static (stays in VGPRs). No LDS, no barriers:
//   next row's 5 loads are in flight under current row's 64 FMAs, waits are
//   per-wave counted vmcnt, and 16 waves/CU x ~5KB in flight covers the
//   BW*latency product (~17KB/CU for 6 TB/s).

#define D 4096
#define DG 1024          // D/4 float4 column-groups per row
#define K 16
#define TPB 256
#define RPB 16           // rows per block -> grid (4, 512) = 2048 blocks

typedef float f32x4 __attribute__((ext_vector_type(4)));

__global__ __launch_bounds__(TPB) void quad_enhancer_kernel(
    const float* __restrict__ x, const float* __restrict__ w,
    float* __restrict__ out) {
  const int tid = threadIdx.x;
  const int cg = blockIdx.x * TPB + tid;  // this thread's column-group
  const int b0 = blockIdx.y * RPB;

  const float4* __restrict__ x4 = (const float4*)x;
  const float4* __restrict__ w4 = (const float4*)w;
  f32x4* __restrict__ o4 = (f32x4*)out;

  // Neighbor groups with wrap (only cg >= DG-4 actually wraps).
  const int g1 = (cg + 1) & (DG - 1);
  const int g2 = (cg + 2) & (DG - 1);
  const int g3 = (cg + 3) & (DG - 1);
  const int g4 = (cg + 4) & (DG - 1);

  // w[:, 4cg..4cg+3]: load once, then PIN. The empty asm makes each value
  // opaque to the compiler -> it cannot rematerialize (reload) them inside
  // the row loop, so all 64 VGPRs stay live for all RPB rows.
  float4 wv[K];
#pragma unroll
  for (int i = 0; i < K; ++i) wv[i] = w4[i * DG + cg];
#pragma unroll
  for (int i = 0; i < K; ++i) {
    asm volatile("" : "+v"(wv[i].x), "+v"(wv[i].y), "+v"(wv[i].z),
                      "+v"(wv[i].w));
  }

  auto loadrow = [&](int r, float4* buf) {
    const float4* __restrict__ xr = x4 + (size_t)(b0 + r) * DG;
    buf[0] = xr[cg];
    buf[1] = xr[g1];
    buf[2] = xr[g2];
    buf[3] = xr[g3];
    buf[4] = xr[g4];
  };

  auto compute_store = [&](int r, const float4* buf) {
    float xs[20];
#pragma unroll
    for (int j = 0; j < 5; ++j) {  // static indices only -> VGPRs
      xs[4 * j + 0] = buf[j].x;
      xs[4 * j + 1] = buf[j].y;
      xs[4 * j + 2] = buf[j].z;
      xs[4 * j + 3] = buf[j].w;
    }
    float ax = 1.0f, ay = 1.0f, az = 1.0f, aw = 1.0f;
#pragma unroll
    for (int i = 0; i < K; ++i) {
      ax = fmaf(wv[i].x, xs[i + 1], ax);
      ay = fmaf(wv[i].y, xs[i + 2], ay);
      az = fmaf(wv[i].z, xs[i + 3], az);
      aw = fmaf(wv[i].w, xs[i + 4], aw);
    }
    f32x4 o;
    o.x = xs[0] * ax;
    o.y = xs[1] * ay;
    o.z = xs[2] * az;
    o.w = xs[3] * aw;
    __builtin_nontemporal_store(o, &o4[(size_t)(b0 + r) * DG + cg]);
  };

  // Ping-pong prefetch, fully unrolled (8 iterations, static A/B indexing).
  float4 A[5], B[5];
  loadrow(0, A);
#pragma unroll
  for (int r = 0; r < RPB; r += 2) {
    loadrow(r + 1, B);                   // in flight under A's compute
    compute_store(r, A);
    if (r + 2 < RPB) loadrow(r + 2, A);  // in flight under B's compute
    compute_store(r + 1, B);
  }
}

extern "C" void kernel_launch(void* const* d_in, const int* in_sizes, int n_in,
                              void* d_out, int out_size, void* d_ws, size_t ws_size,
                              hipStream_t stream) {
  const float* x = (const float*)d_in[0];
  const float* w = (const float*)d_in[1];
  float* out = (float*)d_out;
  const int B = in_sizes[0] / D;  // 8192

  dim3 grid(DG / TPB, B / RPB);   // (4, 512) = 2048 blocks, 8/CU
  quad_enhancer_kernel<<<grid, TPB, 0, stream>>>(x, w, out);
}

// Round 5
// 242.851 us; speedup vs baseline: 1.3924x; 1.1435x over previous
//
#include <hip/hip_runtime.h>

// z[b,d] = x[b,d] * (1 + sum_{i=1..K} w[i-1,d] * x[b,(d+i) mod D])
// B=8192, D=4096, K=16, fp32. HBM floor: ~204 MB real traffic -> ~32 us.
//
// R2 (86 us, best): LDS burst-stage + barrier. wv[16] stayed in regs
//   (VGPR=92) because the compute loop reads LDS (low pressure). Defect:
//   stage issued right before its own vmcnt(0) drain -> full HBM latency
//   exposed every tile, zero loads in flight during compute.
// R3/R5 (96/119 us): reg-pipeline variants. Compiler remat'd (R3, VGPR=68)
//   or spilled (R5, VGPR=60) the 64-reg wv array. Lesson: don't fight
//   regalloc with global-load pipelines; keep R2's LDS compute shape.
// R4 (187 us): no w reuse -> 2.1 GB L1/L2 w-traffic, L1 thrash. Mandatory
//   to reuse w across rows.
// R6 (this): R2 + DOUBLE-BUFFERED LDS tiles (T3 2-phase pattern). Stage
//   tile t+1 into buf q BEFORE computing tile t from buf p. The barrier's
//   vmcnt drain then waits on loads issued a full compute phase earlier ->
//   stall ~0; steady state = max(compute, BW) not sum. 4-row tiles, 8
//   tiles/block, LDS 2x16.6KB = 33280 B -> 4 blocks/CU (same as R2).

#define D 4096
#define DG 1024          // D/4 float4 column-groups per row
#define K 16
#define TPB 256
#define TILE_B 4         // rows per tile (per LDS buffer)
#define NT 8             // tiles per block -> 32 rows/block
#define ROW_F4 260       // 256 groups + 4 halo groups
#define ROW_F (ROW_F4 * 4)
#define BUF_F (TILE_B * ROW_F)   // 4160 floats per buffer

typedef float f32x4 __attribute__((ext_vector_type(4)));

__global__ __launch_bounds__(TPB) void quad_enhancer_kernel(
    const float* __restrict__ x, const float* __restrict__ w,
    float* __restrict__ out) {
  __shared__ float lds[2 * BUF_F];  // 33280 B

  const int tid = threadIdx.x;
  const int cg0 = blockIdx.x * TPB;
  const int cg = cg0 + tid;
  const int b0 = blockIdx.y * (TILE_B * NT);

  const float4* __restrict__ x4 = (const float4*)x;
  const float4* __restrict__ w4 = (const float4*)w;
  f32x4* __restrict__ o4 = (f32x4*)out;

  const int hr = tid >> 2;        // halo row (0..3) for tid<16
  const int hj = tid & 3;         // halo group (0..3)
  const int hg = (cg0 + 256 + hj) & (DG - 1);  // wrapped halo column-group

  // Issue stage of tile t into LDS buffer q (async, no VGPR round-trip).
  auto stage = [&](int t, int q) {
#pragma unroll
    for (int r = 0; r < TILE_B; ++r) {
      const float4* gptr = &x4[(size_t)(b0 + t * TILE_B + r) * DG + cg];
      float* lptr = &lds[q * BUF_F + r * ROW_F + tid * 4];
      __builtin_amdgcn_global_load_lds(
          (const __attribute__((address_space(1))) void*)gptr,
          (__attribute__((address_space(3))) void*)lptr, 16, 0, 0);
    }
  };

  // ---- prologue: stage tile 0, wv loads, halo(0) ----
  stage(0, 0);

  // w[:, 4cg..4cg+3] in registers, reused for all 32 rows (R2-proven shape).
  float4 wv[K];
#pragma unroll
  for (int i = 0; i < K; ++i) wv[i] = w4[i * DG + cg];

  if (tid < TILE_B * 4) {
    float4 h0 = x4[(size_t)(b0 + hr) * DG + hg];
    *(float4*)&lds[hr * ROW_F + (256 + hj) * 4] = h0;
  }
  __syncthreads();  // tile 0 staged

#pragma unroll 1
  for (int t = 0; t < NT; ++t) {
    const int p = t & 1;
    const int q = p ^ 1;

    // Prefetch tile t+1 (in flight under this tile's compute).
    float4 haloN;
    if (t + 1 < NT) {
      stage(t + 1, q);
      if (tid < TILE_B * 4) {
        haloN = x4[(size_t)(b0 + (t + 1) * TILE_B + hr) * DG + hg];
      }
    }

    // Compute tile t from buffer p (LDS reads + FMAs, wv in regs).
#pragma unroll 2
    for (int r = 0; r < TILE_B; ++r) {
      const float4* lrow = (const float4*)&lds[p * BUF_F + r * ROW_F];
      float xs[20];
#pragma unroll
      for (int j = 0; j < 5; ++j) {  // 5 x ds_read_b128
        float4 v = lrow[tid + j];
        xs[4 * j + 0] = v.x;
        xs[4 * j + 1] = v.y;
        xs[4 * j + 2] = v.z;
        xs[4 * j + 3] = v.w;
      }
      float ax = 1.0f, ay = 1.0f, az = 1.0f, aw = 1.0f;
#pragma unroll
      for (int i = 0; i < K; ++i) {
        ax = fmaf(wv[i].x, xs[i + 1], ax);
        ay = fmaf(wv[i].y, xs[i + 2], ay);
        az = fmaf(wv[i].z, xs[i + 3], az);
        aw = fmaf(wv[i].w, xs[i + 4], aw);
      }
      f32x4 o;
      o.x = xs[0] * ax;
      o.y = xs[1] * ay;
      o.z = xs[2] * az;
      o.w = xs[3] * aw;
      __builtin_nontemporal_store(
          o, &o4[(size_t)(b0 + t * TILE_B + r) * DG + cg]);
    }

    // Land halo(t+1) then barrier: vmcnt drain waits on loads issued a
    // full compute phase ago -> ~no stall.
    if (t + 1 < NT) {
      if (tid < TILE_B * 4) {
        *(float4*)&lds[q * BUF_F + hr * ROW_F + (256 + hj) * 4] = haloN;
      }
      __syncthreads();
    }
  }
}

extern "C" void kernel_launch(void* const* d_in, const int* in_sizes, int n_in,
                              void* d_out, int out_size, void* d_ws, size_t ws_size,
                              hipStream_t stream) {
  const float* x = (const float*)d_in[0];
  const float* w = (const float*)d_in[1];
  float* out = (float*)d_out;
  const int B = in_sizes[0] / D;  // 8192

  dim3 grid(DG / TPB, B / (TILE_B * NT));  // (4, 256) = 1024 blocks, 4/CU
  quad_enhancer_kernel<<<grid, TPB, 0, stream>>>(x, w, out);
}